// Round 1
// baseline (2488.153 us; speedup 1.0000x reference)
//
#include <hip/hip_runtime.h>
#include <hip/hip_bf16.h>

#define BB 64
#define SS 2048
#define II 64
#define HH 128

__device__ __forceinline__ float sigm(float x) { return 1.0f / (1.0f + __expf(-x)); }
__device__ __forceinline__ float tanh_fast(float x) {
  x = fminf(fmaxf(x, -12.f), 12.f);
  float e = __expf(2.f * x);
  return (e - 1.f) / (e + 1.f);
}

// wx0[b,s,j] = sum_i x[b,s,i] * w0[i,j]
__global__ __launch_bounds__(256, 4)
void wx0_kernel(const float* __restrict__ x, const float* __restrict__ w0,
                float* __restrict__ wx0) {
  __shared__ float xs[32][64];
  const int tid = threadIdx.x;
  const int j = tid & (HH - 1);
  const int rh = tid >> 7;
  const long row0 = (long)blockIdx.x * 32;

  float w0c[II];
#pragma unroll
  for (int i = 0; i < II; ++i) w0c[i] = w0[i * HH + j];

  const float4* xg = (const float4*)(x + row0 * II);
  float4* xsv = (float4*)&xs[0][0];
  xsv[tid] = xg[tid];
  xsv[tid + 256] = xg[tid + 256];
  __syncthreads();

#pragma unroll
  for (int rp = 0; rp < 16; ++rp) {
    int r = rp * 2 + rh;
    float acc = 0.f;
#pragma unroll
    for (int i = 0; i < II; i += 4) {
      float4 xv = *(const float4*)&xs[r][i];
      acc += w0c[i] * xv.x + w0c[i + 1] * xv.y + w0c[i + 2] * xv.z +
             w0c[i + 3] * xv.w;
    }
    wx0[(row0 + r) * HH + j] = acc;
  }
}

// Fused 2-layer scan. One block per batch element. 256 threads:
// j = tid&127 (output feature), half = tid>>7 (k-range split of the matvecs).
// Recurrent weights u0, w1, u1 held in registers (64 each per thread).
__global__ __launch_bounds__(256, 1)
void scan_kernel(const float* __restrict__ wx0,
                 const float* __restrict__ u0, const float* __restrict__ bg0,
                 const float* __restrict__ bu0, const float* __restrict__ zeta0,
                 const float* __restrict__ nu0, const float* __restrict__ lambd0,
                 const float* __restrict__ gamma0,
                 const float* __restrict__ w1, const float* __restrict__ u1,
                 const float* __restrict__ bg1, const float* __restrict__ bu1,
                 const float* __restrict__ zeta1, const float* __restrict__ nu1,
                 const float* __restrict__ lambd1, const float* __restrict__ gamma1,
                 float* __restrict__ out1, float* __restrict__ hn) {
  const int b = blockIdx.x;
  const int tid = threadIdx.x;
  const int j = tid & (HH - 1);
  const int half = tid >> 7;
  const int kbase = half * 64;

  float u0r[64], w1r[64], u1r[64];
#pragma unroll
  for (int kk = 0; kk < 64; ++kk) {
    u0r[kk] = u0[(kbase + kk) * HH + j];
    w1r[kk] = w1[(kbase + kk) * HH + j];
    u1r[kk] = u1[(kbase + kk) * HH + j];
  }

  const float sz0 = sigm(zeta0[0]), sn0 = sigm(nu0[0]);
  const float gc0 = fminf(fmaxf(gamma0[0], 0.f), 1.f);
  const float lam0 = lambd0[0];
  const float sz1 = sigm(zeta1[0]), sn1 = sigm(nu1[0]);
  const float gc1 = fminf(fmaxf(gamma1[0], 0.f), 1.f);
  const float lam1 = lambd1[0];
  const float bg0j = bg0[j], bu0j = bu0[j];
  const float bg1j = bg1[j], bu1j = bu1[j];

  __shared__ __align__(16) float hs0[HH];  // h of layer0; also out0_t broadcast
  __shared__ __align__(16) float hs1[HH];  // h of layer1
  __shared__ float p0[HH], p1[HH], pw[HH]; // cross-half partial sums

  if (tid < HH) { hs0[tid] = 0.f; hs1[tid] = 0.f; }
  __syncthreads();

  const float* wxp = wx0 + (size_t)b * SS * HH + j;
  float* outp = out1 + (size_t)b * SS * HH + j;

  float last_h0 = 0.f, last_h1 = 0.f;

  auto step = [&](float wxv, int t) {
    // matvecs A (h0@u0) and C (h1@u1), each half sums its 64 k's
    float acc0 = 0.f, acc1 = 0.f;
#pragma unroll
    for (int kk = 0; kk < 64; kk += 4) {
      float4 h0v = *(const float4*)&hs0[kbase + kk];
      float4 h1v = *(const float4*)&hs1[kbase + kk];
      acc0 += u0r[kk] * h0v.x;     acc1 += u1r[kk] * h1v.x;
      acc0 += u0r[kk + 1] * h0v.y; acc1 += u1r[kk + 1] * h1v.y;
      acc0 += u0r[kk + 2] * h0v.z; acc1 += u1r[kk + 2] * h1v.z;
      acc0 += u0r[kk + 3] * h0v.w; acc1 += u1r[kk + 3] * h1v.w;
    }
    if (half) { p0[j] = acc0; p1[j] = acc1; }
    __syncthreads();
    if (!half) {
      float pre0 = wxv + acc0 + p0[j];
      float z = sigm(pre0 + bg0j);
      float hh = tanh_fast(pre0 + bu0j);
      float h0 = hs0[j];
      float h0n = z * h0 + (sz0 * (1.f - z) + sn0) * hh;
      float h0c = gc0 * h0n + (1.f - gc0) * lam0;
      hs0[j] = h0c;  // hs0 now holds out0_t
      last_h0 = h0c;
      acc1 += p1[j];  // full layer-1 recurrent sum, kept for later
    }
    __syncthreads();
    // matvec B: out0_t @ w1
    float accw = 0.f;
#pragma unroll
    for (int kk = 0; kk < 64; kk += 4) {
      float4 ov = *(const float4*)&hs0[kbase + kk];
      accw += w1r[kk] * ov.x;
      accw += w1r[kk + 1] * ov.y;
      accw += w1r[kk + 2] * ov.z;
      accw += w1r[kk + 3] * ov.w;
    }
    if (half) { pw[j] = accw; }
    __syncthreads();
    if (!half) {
      float pre1 = accw + pw[j] + acc1;
      float z1 = sigm(pre1 + bg1j);
      float hh1 = tanh_fast(pre1 + bu1j);
      float h1 = hs1[j];
      float h1n = z1 * h1 + (sz1 * (1.f - z1) + sn1) * hh1;
      float h1c = gc1 * h1n + (1.f - gc1) * lam1;
      hs1[j] = h1c;
      last_h1 = h1c;
      outp[(size_t)t * HH] = h1c;
    }
    __syncthreads();
  };

  // main loop, unroll 2, prefetch wx two steps ahead
  float wxA = wxp[0];
  float wxB = wxp[HH];
  for (int t = 0; t < SS; t += 2) {
    int tn0 = t + 2 < SS ? t + 2 : SS - 1;
    float wxN0 = wxp[(size_t)tn0 * HH];
    step(wxA, t);
    int tn1 = t + 3 < SS ? t + 3 : SS - 1;
    float wxN1 = wxp[(size_t)tn1 * HH];
    step(wxB, t + 1);
    wxA = wxN0;
    wxB = wxN1;
  }

  if (!half) {
    hn[b * HH + j] = last_h0;
    hn[BB * HH + b * HH + j] = last_h1;
  }
}

extern "C" void kernel_launch(void* const* d_in, const int* in_sizes, int n_in,
                              void* d_out, int out_size, void* d_ws, size_t ws_size,
                              hipStream_t stream) {
  const float* x      = (const float*)d_in[0];
  const float* w0     = (const float*)d_in[1];
  const float* u0     = (const float*)d_in[2];
  const float* bg0    = (const float*)d_in[3];
  const float* bu0    = (const float*)d_in[4];
  const float* zeta0  = (const float*)d_in[5];
  const float* nu0    = (const float*)d_in[6];
  const float* lambd0 = (const float*)d_in[7];
  const float* gamma0 = (const float*)d_in[8];
  const float* w1     = (const float*)d_in[9];
  const float* u1     = (const float*)d_in[10];
  const float* bg1    = (const float*)d_in[11];
  const float* bu1    = (const float*)d_in[12];
  const float* zeta1  = (const float*)d_in[13];
  const float* nu1    = (const float*)d_in[14];
  const float* lambd1 = (const float*)d_in[15];
  const float* gamma1 = (const float*)d_in[16];

  float* out = (float*)d_out;                     // out1: [B,S,H]
  float* hn  = out + (size_t)BB * SS * HH;        // h_n:  [2,B,H]
  float* wx0 = (float*)d_ws;                      // scratch: [B,S,H] fp32 (64 MB)

  wx0_kernel<<<(BB * SS) / 32, 256, 0, stream>>>(x, w0, wx0);
  scan_kernel<<<BB, 256, 0, stream>>>(wx0, u0, bg0, bu0, zeta0, nu0, lambd0,
                                      gamma0, w1, u1, bg1, bu1, zeta1, nu1,
                                      lambd1, gamma1, out, hn);
}

// Round 3
// 1488.024 us; speedup vs baseline: 1.6721x; 1.6721x over previous
//
#include <hip/hip_runtime.h>
#include <hip/hip_bf16.h>

#define BB 64
#define SS 2048
#define II 64
#define HH 128
#define CH 64   // timestep chunk staged in LDS

typedef _Float16 h2t __attribute__((ext_vector_type(2)));

__device__ __forceinline__ float sigm(float x) { return 1.0f / (1.0f + __expf(-x)); }
__device__ __forceinline__ float tanh_fast(float x) {
  x = fminf(fmaxf(x, -12.f), 12.f);
  float e = __expf(2.f * x);
  return (e - 1.f) / (e + 1.f);
}

template <int CTRL>
__device__ __forceinline__ float dpp_xadd(float v, float src) {
  // v + (src swizzled by DPP ctrl); ctrl must be a compile-time constant
  int s = __builtin_amdgcn_update_dpp(0, __float_as_int(src), CTRL, 0xF, 0xF, true);
  return v + __int_as_float(s);
}

// reduce-scatter over 8 kparts (lane bits 0..2): lane ends with the full sum
// for output offset (kpart&3); 2-redundant across lane^4.
__device__ __forceinline__ float sreduce(float a0, float a1, float a2, float a3,
                                         bool b0, bool b1) {
  float k0 = b0 ? a1 : a0, d0 = b0 ? a0 : a1;
  float k1 = b0 ? a3 : a2, d1 = b0 ? a2 : a3;
  float r0 = dpp_xadd<0xB1>(k0, d0);  // quad_perm [1,0,3,2] = xor1
  float r1 = dpp_xadd<0xB1>(k1, d1);
  float kk = b1 ? r1 : r0, dd = b1 ? r0 : r1;
  float s = dpp_xadd<0x4E>(kk, dd);   // quad_perm [2,3,0,1] = xor2
  // xor4 via ds_swizzle (BitMode xor_mask=4)
  s += __int_as_float(__builtin_amdgcn_ds_swizzle(__float_as_int(s), 0x101F));
  return s;
}

// wx0[b,s,j] = sum_i x[b,s,i] * w0[i,j]
__global__ __launch_bounds__(256, 4)
void wx0_kernel(const float* __restrict__ x, const float* __restrict__ w0,
                float* __restrict__ wx0) {
  __shared__ float xs[32][64];
  const int tid = threadIdx.x;
  const int j = tid & (HH - 1);
  const int rh = tid >> 7;
  const long row0 = (long)blockIdx.x * 32;

  float w0c[II];
#pragma unroll
  for (int i = 0; i < II; ++i) w0c[i] = w0[i * HH + j];

  const float4* xg = (const float4*)(x + row0 * II);
  float4* xsv = (float4*)&xs[0][0];
  xsv[tid] = xg[tid];
  xsv[tid + 256] = xg[tid + 256];
  __syncthreads();

#pragma unroll
  for (int rp = 0; rp < 16; ++rp) {
    int r = rp * 2 + rh;
    float acc = 0.f;
#pragma unroll
    for (int i = 0; i < II; i += 4) {
      float4 xv = *(const float4*)&xs[r][i];
      acc += w0c[i] * xv.x + w0c[i + 1] * xv.y + w0c[i + 2] * xv.z +
             w0c[i + 3] * xv.w;
    }
    wx0[(row0 + r) * HH + j] = acc;
  }
}

// Fused 2-layer scan. One block per batch element; 256 threads = 4 waves.
// lane: kpart = lane&7 (k-chunk of 16), g = w*8 + (lane>>3) (output quad),
// pre-scatter accumulators for j = 4g+{0..3}; after reduce-scatter the lane
// owns j = 4g + (kpart&3). Weights in packed half2 consumed by v_dot2_f32_f16.
__global__ __launch_bounds__(256, 1)
void scan_kernel(const float* __restrict__ wx0,
                 const float* __restrict__ u0, const float* __restrict__ bg0,
                 const float* __restrict__ bu0, const float* __restrict__ zeta0,
                 const float* __restrict__ nu0, const float* __restrict__ lambd0,
                 const float* __restrict__ gamma0,
                 const float* __restrict__ w1, const float* __restrict__ u1,
                 const float* __restrict__ bg1, const float* __restrict__ bu1,
                 const float* __restrict__ zeta1, const float* __restrict__ nu1,
                 const float* __restrict__ lambd1, const float* __restrict__ gamma1,
                 float* __restrict__ out1, float* __restrict__ hn) {
  const int b = blockIdx.x;
  const int tid = threadIdx.x;
  const int lane = tid & 63;
  const int w = tid >> 6;
  const int kpart = lane & 7;
  const int g = w * 8 + (lane >> 3);
  const int j4 = g * 4;
  const int j = j4 + (kpart & 3);          // owned output after scatter
  const int k0 = kpart * 16;               // k-chunk [k0, k0+16)
  const bool b0 = (kpart & 1) != 0;
  const bool b1 = (kpart & 2) != 0;
  const bool writer = (lane & 4) == 0;     // 1 of the 2 redundant lanes

  // ---- preload weights as half2 pairs: w[k0+2p(+1)][j4+m] ----
  h2t wA[4][8], wB[4][8], wC[4][8];
#pragma unroll
  for (int m = 0; m < 4; ++m) {
#pragma unroll
    for (int p = 0; p < 8; ++p) {
      int kk = k0 + 2 * p;
      wA[m][p] = h2t{(_Float16)u0[kk * HH + j4 + m], (_Float16)u0[(kk + 1) * HH + j4 + m]};
      wB[m][p] = h2t{(_Float16)w1[kk * HH + j4 + m], (_Float16)w1[(kk + 1) * HH + j4 + m]};
      wC[m][p] = h2t{(_Float16)u1[kk * HH + j4 + m], (_Float16)u1[(kk + 1) * HH + j4 + m]};
    }
  }

  const float sz0 = sigm(zeta0[0]), sn0 = sigm(nu0[0]);
  const float gc0 = fminf(fmaxf(gamma0[0], 0.f), 1.f);
  const float k0c = (1.f - gc0) * lambd0[0];
  const float sz1 = sigm(zeta1[0]), sn1 = sigm(nu1[0]);
  const float gc1 = fminf(fmaxf(gamma1[0], 0.f), 1.f);
  const float k1c = (1.f - gc1) * lambd1[0];
  const float bg0j = bg0[j], bu0j = bu0[j];
  const float bg1j = bg1[j], bu1j = bu1[j];

  __shared__ __align__(16) _Float16 hs0[HH];
  __shared__ __align__(16) _Float16 hs1[HH];
  __shared__ float wxbuf[CH * HH];   // 32 KB
  __shared__ float outbuf[CH * HH];  // 32 KB

  if (tid < HH) { hs0[tid] = (_Float16)0.f; hs1[tid] = (_Float16)0.f; }

  const float* wxg = wx0 + (size_t)b * SS * HH;
  float* outg = out1 + (size_t)b * SS * HH;

  // initial wx chunk (t = 0..63)
#pragma unroll
  for (int i = 0; i < 32; ++i) {
    int idx = i * 256 + tid;
    wxbuf[idx] = wxg[idx];
  }
  __syncthreads();

  float h0p = 0.f, h1p = 0.f;

  for (int t = 0; t < SS; ++t) {
    const int toff = (t & (CH - 1)) * HH;
    float wxv = wxbuf[toff + j];

    // ---- phase 1: A = h0@u0, C = h1@u1 ----
    uint4 ua = *(const uint4*)&hs0[k0];
    uint4 ub = *(const uint4*)&hs0[k0 + 8];
    uint4 va = *(const uint4*)&hs1[k0];
    uint4 vb = *(const uint4*)&hs1[k0 + 8];
    h2t hp[8], gp[8];
    hp[0] = __builtin_bit_cast(h2t, ua.x); hp[1] = __builtin_bit_cast(h2t, ua.y);
    hp[2] = __builtin_bit_cast(h2t, ua.z); hp[3] = __builtin_bit_cast(h2t, ua.w);
    hp[4] = __builtin_bit_cast(h2t, ub.x); hp[5] = __builtin_bit_cast(h2t, ub.y);
    hp[6] = __builtin_bit_cast(h2t, ub.z); hp[7] = __builtin_bit_cast(h2t, ub.w);
    gp[0] = __builtin_bit_cast(h2t, va.x); gp[1] = __builtin_bit_cast(h2t, va.y);
    gp[2] = __builtin_bit_cast(h2t, va.z); gp[3] = __builtin_bit_cast(h2t, va.w);
    gp[4] = __builtin_bit_cast(h2t, vb.x); gp[5] = __builtin_bit_cast(h2t, vb.y);
    gp[6] = __builtin_bit_cast(h2t, vb.z); gp[7] = __builtin_bit_cast(h2t, vb.w);

    float a0 = 0.f, a1 = 0.f, a2 = 0.f, a3 = 0.f;
    float c0 = 0.f, c1 = 0.f, c2 = 0.f, c3 = 0.f;
#pragma unroll
    for (int p = 0; p < 8; ++p) {
      a0 = __builtin_amdgcn_fdot2(hp[p], wA[0][p], a0, false);
      a1 = __builtin_amdgcn_fdot2(hp[p], wA[1][p], a1, false);
      a2 = __builtin_amdgcn_fdot2(hp[p], wA[2][p], a2, false);
      a3 = __builtin_amdgcn_fdot2(hp[p], wA[3][p], a3, false);
      c0 = __builtin_amdgcn_fdot2(gp[p], wC[0][p], c0, false);
      c1 = __builtin_amdgcn_fdot2(gp[p], wC[1][p], c1, false);
      c2 = __builtin_amdgcn_fdot2(gp[p], wC[2][p], c2, false);
      c3 = __builtin_amdgcn_fdot2(gp[p], wC[3][p], c3, false);
    }
    float asum = sreduce(a0, a1, a2, a3, b0, b1);
    float csum = sreduce(c0, c1, c2, c3, b0, b1);

    // gate 0 (all lanes, 2-redundant)
    float pre0 = asum + wxv;
    float z0 = sigm(pre0 + bg0j);
    float hh0 = tanh_fast(pre0 + bu0j);
    float h0n = gc0 * (z0 * h0p + (sz0 * (1.f - z0) + sn0) * hh0) + k0c;
    h0p = h0n;
    if (writer) hs0[j] = (_Float16)h0n;
    __syncthreads();

    // ---- phase 2: B = o0@w1 ----
    uint4 wa = *(const uint4*)&hs0[k0];
    uint4 wb = *(const uint4*)&hs0[k0 + 8];
    h2t op[8];
    op[0] = __builtin_bit_cast(h2t, wa.x); op[1] = __builtin_bit_cast(h2t, wa.y);
    op[2] = __builtin_bit_cast(h2t, wa.z); op[3] = __builtin_bit_cast(h2t, wa.w);
    op[4] = __builtin_bit_cast(h2t, wb.x); op[5] = __builtin_bit_cast(h2t, wb.y);
    op[6] = __builtin_bit_cast(h2t, wb.z); op[7] = __builtin_bit_cast(h2t, wb.w);

    float e0 = 0.f, e1 = 0.f, e2 = 0.f, e3 = 0.f;
#pragma unroll
    for (int p = 0; p < 8; ++p) {
      e0 = __builtin_amdgcn_fdot2(op[p], wB[0][p], e0, false);
      e1 = __builtin_amdgcn_fdot2(op[p], wB[1][p], e1, false);
      e2 = __builtin_amdgcn_fdot2(op[p], wB[2][p], e2, false);
      e3 = __builtin_amdgcn_fdot2(op[p], wB[3][p], e3, false);
    }
    float bsum = sreduce(e0, e1, e2, e3, b0, b1);

    // gate 1
    float pre1 = bsum + csum;
    float z1 = sigm(pre1 + bg1j);
    float hh1 = tanh_fast(pre1 + bu1j);
    float h1n = gc1 * (z1 * h1p + (sz1 * (1.f - z1) + sn1) * hh1) + k1c;
    h1p = h1n;
    if (writer) {
      hs1[j] = (_Float16)h1n;
      outbuf[toff + j] = h1n;
    }
    __syncthreads();

    // ---- chunk boundary: flush out, load next wx ----
    if ((t & (CH - 1)) == (CH - 1)) {
      const int tbase = t - (CH - 1);
#pragma unroll
      for (int i = 0; i < 32; ++i) {
        int idx = i * 256 + tid;
        outg[(size_t)tbase * HH + idx] = outbuf[idx];
      }
      if (t + 1 < SS) {
#pragma unroll
        for (int i = 0; i < 32; ++i) {
          int idx = i * 256 + tid;
          wxbuf[idx] = wxg[(size_t)(t + 1) * HH + idx];
        }
      }
      __syncthreads();
    }
  }

  if (writer) {
    hn[b * HH + j] = h0p;
    hn[BB * HH + b * HH + j] = h1p;
  }
}

extern "C" void kernel_launch(void* const* d_in, const int* in_sizes, int n_in,
                              void* d_out, int out_size, void* d_ws, size_t ws_size,
                              hipStream_t stream) {
  const float* x      = (const float*)d_in[0];
  const float* w0     = (const float*)d_in[1];
  const float* u0     = (const float*)d_in[2];
  const float* bg0    = (const float*)d_in[3];
  const float* bu0    = (const float*)d_in[4];
  const float* zeta0  = (const float*)d_in[5];
  const float* nu0    = (const float*)d_in[6];
  const float* lambd0 = (const float*)d_in[7];
  const float* gamma0 = (const float*)d_in[8];
  const float* w1     = (const float*)d_in[9];
  const float* u1     = (const float*)d_in[10];
  const float* bg1    = (const float*)d_in[11];
  const float* bu1    = (const float*)d_in[12];
  const float* zeta1  = (const float*)d_in[13];
  const float* nu1    = (const float*)d_in[14];
  const float* lambd1 = (const float*)d_in[15];
  const float* gamma1 = (const float*)d_in[16];

  float* out = (float*)d_out;                     // out1: [B,S,H]
  float* hn  = out + (size_t)BB * SS * HH;        // h_n:  [2,B,H]
  float* wx0 = (float*)d_ws;                      // scratch: [B,S,H] fp32 (64 MB)

  wx0_kernel<<<(BB * SS) / 32, 256, 0, stream>>>(x, w0, wx0);
  scan_kernel<<<BB, 256, 0, stream>>>(wx0, u0, bg0, bu0, zeta0, nu0, lambd0,
                                      gamma0, w1, u1, bg1, bu1, zeta1, nu1,
                                      lambd1, gamma1, out, hn);
}

// Round 4
// 1128.183 us; speedup vs baseline: 2.2055x; 1.3190x over previous
//
#include <hip/hip_runtime.h>
#include <hip/hip_bf16.h>

#define BB 64
#define SS 2048
#define II 64
#define HH 128
#define CH 64   // timestep chunk staged in LDS

typedef _Float16 h2t __attribute__((ext_vector_type(2)));

__device__ __forceinline__ float sigm(float x) { return 1.0f / (1.0f + __expf(-x)); }
__device__ __forceinline__ float tanh_fast(float x) {
  x = fminf(fmaxf(x, -12.f), 12.f);
  float e = __expf(2.f * x);
  return (e - 1.f) / (e + 1.f);
}

template <int CTRL>
__device__ __forceinline__ float dpp_xadd(float v, float src) {
  int s = __builtin_amdgcn_update_dpp(0, __float_as_int(src), CTRL, 0xF, 0xF, true);
  return v + __int_as_float(s);
}

// 4-way reduce-scatter within each quad (kpart = lane&3, k-chunks of 32).
// s0 = partial for output 2g, s1 = partial for output 2g+1.
// Returns full 128-k sum for owned output j = 2g + (kpart&1).
__device__ __forceinline__ float reduce4(float s0, float s1, bool b0) {
  float k = b0 ? s1 : s0;            // keep own output's partial
  float d = b0 ? s0 : s1;            // send partner output's partial
  float r = dpp_xadd<0xB1>(k, d);    // quad_perm [1,0,3,2] : xor1
  r = dpp_xadd<0x4E>(r, r);          // quad_perm [2,3,0,1] : xor2
  return r;
}

// wx0[b,s,j] = sum_i x[b,s,i] * w0[i,j]
__global__ __launch_bounds__(256, 4)
void wx0_kernel(const float* __restrict__ x, const float* __restrict__ w0,
                float* __restrict__ wx0) {
  __shared__ float xs[32][64];
  const int tid = threadIdx.x;
  const int j = tid & (HH - 1);
  const int rh = tid >> 7;
  const long row0 = (long)blockIdx.x * 32;

  float w0c[II];
#pragma unroll
  for (int i = 0; i < II; ++i) w0c[i] = w0[i * HH + j];

  const float4* xg = (const float4*)(x + row0 * II);
  float4* xsv = (float4*)&xs[0][0];
  xsv[tid] = xg[tid];
  xsv[tid + 256] = xg[tid + 256];
  __syncthreads();

#pragma unroll
  for (int rp = 0; rp < 16; ++rp) {
    int r = rp * 2 + rh;
    float acc = 0.f;
#pragma unroll
    for (int i = 0; i < II; i += 4) {
      float4 xv = *(const float4*)&xs[r][i];
      acc += w0c[i] * xv.x + w0c[i + 1] * xv.y + w0c[i + 2] * xv.z +
             w0c[i + 3] * xv.w;
    }
    wx0[(row0 + r) * HH + j] = acc;
  }
}

// Fused 2-layer scan with layer skew: iteration n computes
//   h0[n+1] = G0(h0[n], wx[n+1])   via A = h0[n]@u0
//   h1[n]   = G1(h1[n-1], h0[n])   via B = h0[n]@w1, C = h1[n-1]@u1
// All 3 matvecs read only {h0[n], h1[n-1]} -> ONE phase, ONE barrier/step,
// h double-buffered in LDS. Lane mapping: kpart=tid&3 (32 k's), g=tid>>2
// (outputs 2g,2g+1); after quad-DPP reduce lane owns j=2g+(kpart&1);
// kpart&2 lanes are redundant; writer = (kpart&2)==0.
__global__ __launch_bounds__(256, 1)
void scan_kernel(const float* __restrict__ wx0,
                 const float* __restrict__ u0, const float* __restrict__ bg0,
                 const float* __restrict__ bu0, const float* __restrict__ zeta0,
                 const float* __restrict__ nu0, const float* __restrict__ lambd0,
                 const float* __restrict__ gamma0,
                 const float* __restrict__ w1, const float* __restrict__ u1,
                 const float* __restrict__ bg1, const float* __restrict__ bu1,
                 const float* __restrict__ zeta1, const float* __restrict__ nu1,
                 const float* __restrict__ lambd1, const float* __restrict__ gamma1,
                 float* __restrict__ out1, float* __restrict__ hn) {
  const int b = blockIdx.x;
  const int tid = threadIdx.x;
  const int kpart = tid & 3;
  const int g = tid >> 2;
  const int j = 2 * g + (kpart & 1);
  const int k0 = kpart * 32;           // k-chunk [k0, k0+32)
  const bool b0 = (kpart & 1) != 0;
  const bool writer = (kpart & 2) == 0;

  // ---- weights as half2: w[k0+2p(+1)][2g+m], m in {0,1}, p in [0,16) ----
  h2t wA[2][16], wB[2][16], wC[2][16];
#pragma unroll
  for (int m = 0; m < 2; ++m) {
    const int jc = 2 * g + m;
#pragma unroll
    for (int p = 0; p < 16; ++p) {
      int kk = k0 + 2 * p;
      wA[m][p] = h2t{(_Float16)u0[kk * HH + jc], (_Float16)u0[(kk + 1) * HH + jc]};
      wB[m][p] = h2t{(_Float16)w1[kk * HH + jc], (_Float16)w1[(kk + 1) * HH + jc]};
      wC[m][p] = h2t{(_Float16)u1[kk * HH + jc], (_Float16)u1[(kk + 1) * HH + jc]};
    }
  }

  const float sz0 = sigm(zeta0[0]), sn0 = sigm(nu0[0]);
  const float gc0 = fminf(fmaxf(gamma0[0], 0.f), 1.f);
  const float k0c = (1.f - gc0) * lambd0[0];
  const float sz1 = sigm(zeta1[0]), sn1 = sigm(nu1[0]);
  const float gc1 = fminf(fmaxf(gamma1[0], 0.f), 1.f);
  const float k1c = (1.f - gc1) * lambd1[0];
  const float bg0j = bg0[j], bu0j = bu0[j];
  const float bg1j = bg1[j], bu1j = bu1[j];

  __shared__ __align__(16) _Float16 hs[2][2][HH];  // [buf][layer][j]
  __shared__ float wxbuf[CH * HH];   // 32 KB; chunk c holds wx[64c+1 .. 64c+64]
  __shared__ float outbuf[CH * HH];  // 32 KB; slot q holds h1[64c+q]

  const float* wxg = wx0 + (size_t)b * SS * HH;
  float* outg = out1 + (size_t)b * SS * HH;

  // ---- prologue ----
  // initial wx chunk: rows 1..64
  {
    const float4* src = (const float4*)(wxg + HH);  // row 1
    float4* dst = (float4*)wxbuf;
#pragma unroll
    for (int i = 0; i < 8; ++i) dst[i * 256 + tid] = src[i * 256 + tid];
  }
  // h0[0] = G0(0, wx[0]) ; h1[-1] = 0
  float h0p, h1p = 0.f;
  {
    float wxv0 = wxg[j];
    float z0 = sigm(wxv0 + bg0j);
    float hh0 = tanh_fast(wxv0 + bu0j);
    h0p = gc0 * ((sz0 * (1.f - z0) + sn0) * hh0) + k0c;
    if (writer) {
      hs[0][0][j] = (_Float16)h0p;
      hs[0][1][j] = (_Float16)0.f;
    }
  }
  __syncthreads();

  for (int n = 0; n < SS; ++n) {
    const int rd = n & 1, wr = rd ^ 1;
    const int q = n & (CH - 1);

    // ---- read h0[n], h1[n-1] k-chunks (fp16, 64B each = 4x b128) ----
    const uint4* h0v = (const uint4*)&hs[rd][0][k0];
    const uint4* h1v = (const uint4*)&hs[rd][1][k0];
    uint4 u0a = h0v[0], u0b = h0v[1], u0c = h0v[2], u0d = h0v[3];
    uint4 u1a = h1v[0], u1b = h1v[1], u1c = h1v[2], u1d = h1v[3];
    h2t hp[16], gp[16];
    {
      const uint* pu = (const uint*)&u0a;  // u0a..u0d contiguous? copy safely:
      uint tmp0[16] = {u0a.x,u0a.y,u0a.z,u0a.w, u0b.x,u0b.y,u0b.z,u0b.w,
                       u0c.x,u0c.y,u0c.z,u0c.w, u0d.x,u0d.y,u0d.z,u0d.w};
      uint tmp1[16] = {u1a.x,u1a.y,u1a.z,u1a.w, u1b.x,u1b.y,u1b.z,u1b.w,
                       u1c.x,u1c.y,u1c.z,u1c.w, u1d.x,u1d.y,u1d.z,u1d.w};
      (void)pu;
#pragma unroll
      for (int p = 0; p < 16; ++p) {
        hp[p] = __builtin_bit_cast(h2t, tmp0[p]);
        gp[p] = __builtin_bit_cast(h2t, tmp1[p]);
      }
    }

    float wxv = wxbuf[q * HH + j];  // wx[n+1][j]

    // ---- 3 matvecs: A = h0@u0, B = h0@w1, C = h1@u1 ----
    float a0 = 0.f, a1 = 0.f, e0 = 0.f, e1 = 0.f, c0 = 0.f, c1 = 0.f;
#pragma unroll
    for (int p = 0; p < 16; ++p) {
      a0 = __builtin_amdgcn_fdot2(hp[p], wA[0][p], a0, false);
      a1 = __builtin_amdgcn_fdot2(hp[p], wA[1][p], a1, false);
      e0 = __builtin_amdgcn_fdot2(hp[p], wB[0][p], e0, false);
      e1 = __builtin_amdgcn_fdot2(hp[p], wB[1][p], e1, false);
      c0 = __builtin_amdgcn_fdot2(gp[p], wC[0][p], c0, false);
      c1 = __builtin_amdgcn_fdot2(gp[p], wC[1][p], c1, false);
    }
    float asum = reduce4(a0, a1, b0);
    float bsum = reduce4(e0, e1, b0);
    float csum = reduce4(c0, c1, b0);

    // ---- gate 0: h0[n+1] ----
    float pre0 = asum + wxv;
    float z0 = sigm(pre0 + bg0j);
    float hh0 = tanh_fast(pre0 + bu0j);
    float h0n = gc0 * (z0 * h0p + (sz0 * (1.f - z0) + sn0) * hh0) + k0c;

    // ---- gate 1: h1[n] ----
    float pre1 = bsum + csum;
    float z1 = sigm(pre1 + bg1j);
    float hh1 = tanh_fast(pre1 + bu1j);
    float h1n = gc1 * (z1 * h1p + (sz1 * (1.f - z1) + sn1) * hh1) + k1c;
    h1p = h1n;

    if (writer) {
      hs[wr][0][j] = (_Float16)h0n;
      hs[wr][1][j] = (_Float16)h1n;
      outbuf[q * HH + j] = h1n;
    }
    h0p = (n < SS - 1) ? h0n : h0p;  // keep h0[2047] for hn
    __syncthreads();

    // ---- chunk boundary: flush out, load next wx chunk ----
    if (q == CH - 1) {
      const int tbase = n - (CH - 1);
      float4* dst = (float4*)(outg + (size_t)tbase * HH);
      const float4* srcb = (const float4*)outbuf;
#pragma unroll
      for (int i = 0; i < 8; ++i) dst[i * 256 + tid] = srcb[i * 256 + tid];
      if (n + 1 < SS) {
        // next chunk holds wx rows [n+2 .. n+65], clamped to SS-1
        float4* wdst = (float4*)wxbuf;
#pragma unroll
        for (int i = 0; i < 8; ++i) {
          int flat4 = i * 256 + tid;
          int row = n + 2 + (flat4 >> 5);
          row = row < SS ? row : SS - 1;
          int col4 = flat4 & 31;
          wdst[flat4] = *(const float4*)(wxg + (size_t)row * HH + col4 * 4);
        }
        __syncthreads();
      }
    }
  }

  if (writer) {
    hn[b * HH + j] = h0p;
    hn[BB * HH + b * HH + j] = h1p;
  }
}

extern "C" void kernel_launch(void* const* d_in, const int* in_sizes, int n_in,
                              void* d_out, int out_size, void* d_ws, size_t ws_size,
                              hipStream_t stream) {
  const float* x      = (const float*)d_in[0];
  const float* w0     = (const float*)d_in[1];
  const float* u0     = (const float*)d_in[2];
  const float* bg0    = (const float*)d_in[3];
  const float* bu0    = (const float*)d_in[4];
  const float* zeta0  = (const float*)d_in[5];
  const float* nu0    = (const float*)d_in[6];
  const float* lambd0 = (const float*)d_in[7];
  const float* gamma0 = (const float*)d_in[8];
  const float* w1     = (const float*)d_in[9];
  const float* u1     = (const float*)d_in[10];
  const float* bg1    = (const float*)d_in[11];
  const float* bu1    = (const float*)d_in[12];
  const float* zeta1  = (const float*)d_in[13];
  const float* nu1    = (const float*)d_in[14];
  const float* lambd1 = (const float*)d_in[15];
  const float* gamma1 = (const float*)d_in[16];

  float* out = (float*)d_out;                     // out1: [B,S,H]
  float* hn  = out + (size_t)BB * SS * HH;        // h_n:  [2,B,H]
  float* wx0 = (float*)d_ws;                      // scratch: [B,S,H] fp32 (64 MB)

  wx0_kernel<<<(BB * SS) / 32, 256, 0, stream>>>(x, w0, wx0);
  scan_kernel<<<BB, 256, 0, stream>>>(wx0, u0, bg0, bu0, zeta0, nu0, lambd0,
                                      gamma0, w1, u1, bg1, bu1, zeta1, nu1,
                                      lambd1, gamma1, out, hn);
}

// Round 5
// 919.975 us; speedup vs baseline: 2.7046x; 1.2263x over previous
//
#include <hip/hip_runtime.h>
#include <hip/hip_bf16.h>

#define BB 64
#define SS 2048
#define II 64
#define HH 128
#define CH 64   // timestep chunk of wx staged in LDS

typedef _Float16 half8 __attribute__((ext_vector_type(8)));
typedef float f32x4 __attribute__((ext_vector_type(4)));
struct u64x2 { unsigned long long x, y; };

#define LOG2E 1.44269504088896340736f

__device__ __forceinline__ float sigm(float x) { return 1.0f / (1.0f + __expf(-x)); }

// wx0[b,s,j] = sum_i x[b,s,i] * w0[i,j]   (layout [b][s][j], unchanged)
__global__ __launch_bounds__(256, 4)
void wx0_kernel(const float* __restrict__ x, const float* __restrict__ w0,
                float* __restrict__ wx0) {
  __shared__ float xs[32][64];
  const int tid = threadIdx.x;
  const int j = tid & (HH - 1);
  const int rh = tid >> 7;
  const long row0 = (long)blockIdx.x * 32;

  float w0c[II];
#pragma unroll
  for (int i = 0; i < II; ++i) w0c[i] = w0[i * HH + j];

  const float4* xg = (const float4*)(x + row0 * II);
  float4* xsv = (float4*)&xs[0][0];
  xsv[tid] = xg[tid];
  xsv[tid + 256] = xg[tid + 256];
  __syncthreads();

#pragma unroll
  for (int rp = 0; rp < 16; ++rp) {
    int r = rp * 2 + rh;
    float acc = 0.f;
#pragma unroll
    for (int i = 0; i < II; i += 4) {
      float4 xv = *(const float4*)&xs[r][i];
      acc += w0c[i] * xv.x + w0c[i + 1] * xv.y + w0c[i + 2] * xv.z +
             w0c[i + 3] * xv.w;
    }
    wx0[(row0 + r) * HH + j] = acc;
  }
}

// Fused 2-layer scan, one block per batch element, 256 threads = 4 waves.
// MFMA 16x16x32_f16 as a matvec engine (only A-row 0 real). Wave w owns
// output cols [32w, 32w+32). Layer-skewed: iter n computes
//   h0[n+1] = G0(h0[n], wx[n+1])        (accA = h0@u0)
//   h1[n]   = G1(h1[n-1], h0@w1 + h1@u1) (accB + accC)
// g = (lane>>4): row0 of each D-tile lives on g==0 lanes, reg 0.
// Gate split: g==0 lanes gate layer0, g==1 lanes gate layer1 (pre1 moved
// via one ds_swizzle xor16). h broadcast = 128 f16 per layer in LDS.
__global__ __launch_bounds__(256, 1)
void scan_kernel(const float* __restrict__ wx0,
                 const float* __restrict__ u0, const float* __restrict__ bg0,
                 const float* __restrict__ bu0, const float* __restrict__ zeta0,
                 const float* __restrict__ nu0, const float* __restrict__ lambd0,
                 const float* __restrict__ gamma0,
                 const float* __restrict__ w1, const float* __restrict__ u1,
                 const float* __restrict__ bg1, const float* __restrict__ bu1,
                 const float* __restrict__ zeta1, const float* __restrict__ nu1,
                 const float* __restrict__ lambd1, const float* __restrict__ gamma1,
                 float* __restrict__ out1, float* __restrict__ hn) {
  const int b = blockIdx.x;
  const int tid = threadIdx.x;
  const int w = tid >> 6;
  const int l = tid & 63;
  const int g = l >> 4;
  const int n = l & 15;
  const int c0 = 32 * w + n;
  const int c1 = c0 + 16;
  const bool L1 = (g == 1);

  // ---- weight fragments (f16), B-operand layout: elem i -> k = 32kt + kmap(g,i)
  // kmap(g,i) = 4g+i (i<4), 16+4g+(i-4) (i>=4). Same map used for A => consistent.
  const float* Wm0 = u0; const float* Wm1 = w1; const float* Wm2 = u1;
  half8 wf[3][2][4];
#pragma unroll
  for (int mt = 0; mt < 3; ++mt) {
    const float* W = (mt == 0) ? Wm0 : (mt == 1) ? Wm1 : Wm2;
#pragma unroll
    for (int nt = 0; nt < 2; ++nt) {
      const int col = 32 * w + 16 * nt + n;
#pragma unroll
      for (int kt = 0; kt < 4; ++kt) {
        half8 f;
#pragma unroll
        for (int i = 0; i < 8; ++i) {
          int k = 32 * kt + (i < 4 ? 4 * g + i : 16 + 4 * g + (i - 4));
          f[i] = (_Float16)W[k * HH + col];
        }
        wf[mt][nt][kt] = f;
      }
    }
  }

  // ---- per-group gate constants (g==0 -> layer0, g==1 -> layer1, g>=2 garbage ok)
  const float szg = L1 ? sigm(zeta1[0]) : sigm(zeta0[0]);
  const float sng = L1 ? sigm(nu1[0]) : sigm(nu0[0]);
  const float gcr = L1 ? gamma1[0] : gamma0[0];
  const float gcg = fminf(fmaxf(gcr, 0.f), 1.f);
  const float kcg = (1.f - gcg) * (L1 ? lambd1[0] : lambd0[0]);
  const float ebg_0 = -LOG2E * (L1 ? bg1[c0] : bg0[c0]);
  const float ebg_1 = -LOG2E * (L1 ? bg1[c1] : bg0[c1]);
  const float ebu_0 = -2.f * LOG2E * (L1 ? bu1[c0] : bu0[c0]);
  const float ebu_1 = -2.f * LOG2E * (L1 ? bu1[c1] : bu0[c1]);

  auto gate = [&](float pre, float hp, float eg, float eu) -> float {
    float p  = __builtin_amdgcn_exp2f(__builtin_fmaf(pre, -LOG2E, eg));       // e^{-(pre+bg)}
    float qq = __builtin_amdgcn_exp2f(__builtin_fmaf(pre, -2.f * LOG2E, eu)); // e^{-2(pre+bu)}
    float opp = 1.f + p, opq = 1.f + qq, omq = 1.f - qq;
    float t1 = __builtin_fmaf(sng, opp, szg * p);           // sz*p + sn*(1+p)
    float num = __builtin_fmaf(hp, opq, t1 * omq);          // h(1+q) + t1(1-q)
    float hnew = num * __builtin_amdgcn_rcpf(opp * opq);
    return __builtin_fmaf(gcg, hnew, kcg);
  };

  __shared__ __align__(16) _Float16 Hs[2][2][HH];  // [buf][layer][col]
  __shared__ __align__(16) float wxb[CH * HH];     // 32 KB, chunk holds wx rows t+1..

  const float* wxg = wx0 + (size_t)b * SS * HH;
  float* outg = out1 + (size_t)b * SS * HH;

  // ---- prologue: stage wx rows 1..64
  {
    const float4* src = (const float4*)(wxg + HH);
    float4* dst = (float4*)wxb;
#pragma unroll
    for (int i = 0; i < 8; ++i) dst[i * 256 + tid] = src[i * 256 + tid];
  }
  // h0[0] = G0(0, wx[0]); h1[-1] = 0
  float h_prev0, h_prev1;
  {
    float pr0 = wxg[c0], pr1 = wxg[c1];
    float h00 = gate(pr0, 0.f, ebg_0, ebu_0);
    float h01 = gate(pr1, 0.f, ebg_1, ebu_1);
    h_prev0 = (g == 0) ? h00 : 0.f;
    h_prev1 = (g == 0) ? h01 : 0.f;
    if (g == 0) { Hs[0][0][c0] = (_Float16)h00; Hs[0][0][c1] = (_Float16)h01; }
    if (g == 1) { Hs[0][1][c0] = (_Float16)0.f; Hs[0][1][c1] = (_Float16)0.f; }
  }
  asm volatile("s_waitcnt lgkmcnt(0)" ::: "memory");
  __builtin_amdgcn_s_barrier();

  half8 a0[4], a1[4];
#pragma unroll
  for (int kt = 0; kt < 4; ++kt) { a0[kt] = (half8)(_Float16)0.f; a1[kt] = (half8)(_Float16)0.f; }

  const f32x4 zero = {0.f, 0.f, 0.f, 0.f};

  for (int t = 0; t < SS; ++t) {
    const int rd = t & 1, wr = rd ^ 1;
    const int q = t & (CH - 1);

    // ---- A-fragments: only lanes with (lane&15)==0 carry row 0
    if (n == 0) {
      const _Float16* h0r = &Hs[rd][0][0];
      const _Float16* h1r = &Hs[rd][1][0];
#pragma unroll
      for (int kt = 0; kt < 4; ++kt) {
        u64x2 t0 = { *(const unsigned long long*)(h0r + 32 * kt + 4 * g),
                     *(const unsigned long long*)(h0r + 32 * kt + 16 + 4 * g) };
        a0[kt] = __builtin_bit_cast(half8, t0);
        u64x2 t1v = { *(const unsigned long long*)(h1r + 32 * kt + 4 * g),
                      *(const unsigned long long*)(h1r + 32 * kt + 16 + 4 * g) };
        a1[kt] = __builtin_bit_cast(half8, t1v);
      }
    }

    float wxv0 = wxb[q * HH + c0];
    float wxv1 = wxb[q * HH + c1];

    // ---- 3 matvecs x 2 N-tiles, K-chained
    f32x4 accA0, accA1, accB0, accB1, accC0, accC1;
#pragma unroll
    for (int kt = 0; kt < 4; ++kt) {
      accA0 = __builtin_amdgcn_mfma_f32_16x16x32_f16(a0[kt], wf[0][0][kt], kt ? accA0 : zero, 0, 0, 0);
      accA1 = __builtin_amdgcn_mfma_f32_16x16x32_f16(a0[kt], wf[0][1][kt], kt ? accA1 : zero, 0, 0, 0);
      accB0 = __builtin_amdgcn_mfma_f32_16x16x32_f16(a0[kt], wf[1][0][kt], kt ? accB0 : zero, 0, 0, 0);
      accB1 = __builtin_amdgcn_mfma_f32_16x16x32_f16(a0[kt], wf[1][1][kt], kt ? accB1 : zero, 0, 0, 0);
      accC0 = __builtin_amdgcn_mfma_f32_16x16x32_f16(a1[kt], wf[2][0][kt], kt ? accC0 : zero, 0, 0, 0);
      accC1 = __builtin_amdgcn_mfma_f32_16x16x32_f16(a1[kt], wf[2][1][kt], kt ? accC1 : zero, 0, 0, 0);
    }

    // ---- pre1 = B+C on g0 reg0; move to g1 lanes via xor16 swizzle
    float s0 = accB0[0] + accC0[0];
    float s1 = accB1[0] + accC1[0];
    float sw0 = __int_as_float(__builtin_amdgcn_ds_swizzle(__float_as_int(s0), 0x401F));
    float sw1 = __int_as_float(__builtin_amdgcn_ds_swizzle(__float_as_int(s1), 0x401F));

    float pre0 = (g == 0) ? accA0[0] + wxv0 : sw0;
    float pre1 = (g == 0) ? accA1[0] + wxv1 : sw1;

    float hc0 = gate(pre0, h_prev0, ebg_0, ebu_0);
    float hc1 = gate(pre1, h_prev1, ebg_1, ebu_1);

    if (g < 2) {
      Hs[wr][g][c0] = (_Float16)hc0;
      Hs[wr][g][c1] = (_Float16)hc1;
    }
    if (g == 1) {
      outg[(size_t)t * HH + c0] = hc0;
      outg[(size_t)t * HH + c1] = hc1;
    }
    if (t == SS - 2 && g == 0) {  // h0[2047]
      hn[b * HH + c0] = hc0;
      hn[b * HH + c1] = hc1;
    }
    if (t == SS - 1 && g == 1) {  // h1[2047]
      hn[BB * HH + b * HH + c0] = hc0;
      hn[BB * HH + b * HH + c1] = hc1;
    }
    h_prev0 = hc0;
    h_prev1 = hc1;

    asm volatile("s_waitcnt lgkmcnt(0)" ::: "memory");
    __builtin_amdgcn_s_barrier();

    // ---- chunk boundary: restage wx rows t+2 .. t+65 (clamped)
    if (q == CH - 1 && t + 1 < SS) {
      float4* wdst = (float4*)wxb;
#pragma unroll
      for (int i = 0; i < 8; ++i) {
        int flat4 = i * 256 + tid;
        int row = t + 2 + (flat4 >> 5);
        row = row < SS ? row : SS - 1;
        int col4 = flat4 & 31;
        wdst[flat4] = *(const float4*)(wxg + (size_t)row * HH + col4 * 4);
      }
      asm volatile("s_waitcnt lgkmcnt(0)" ::: "memory");
      __builtin_amdgcn_s_barrier();
    }
  }
}

extern "C" void kernel_launch(void* const* d_in, const int* in_sizes, int n_in,
                              void* d_out, int out_size, void* d_ws, size_t ws_size,
                              hipStream_t stream) {
  const float* x      = (const float*)d_in[0];
  const float* w0     = (const float*)d_in[1];
  const float* u0     = (const float*)d_in[2];
  const float* bg0    = (const float*)d_in[3];
  const float* bu0    = (const float*)d_in[4];
  const float* zeta0  = (const float*)d_in[5];
  const float* nu0    = (const float*)d_in[6];
  const float* lambd0 = (const float*)d_in[7];
  const float* gamma0 = (const float*)d_in[8];
  const float* w1     = (const float*)d_in[9];
  const float* u1     = (const float*)d_in[10];
  const float* bg1    = (const float*)d_in[11];
  const float* bu1    = (const float*)d_in[12];
  const float* zeta1  = (const float*)d_in[13];
  const float* nu1    = (const float*)d_in[14];
  const float* lambd1 = (const float*)d_in[15];
  const float* gamma1 = (const float*)d_in[16];

  float* out = (float*)d_out;                     // out1: [B,S,H]
  float* hn  = out + (size_t)BB * SS * HH;        // h_n:  [2,B,H]
  float* wx0 = (float*)d_ws;                      // scratch: [B,S,H] fp32 (64 MB)

  wx0_kernel<<<(BB * SS) / 32, 256, 0, stream>>>(x, w0, wx0);
  scan_kernel<<<BB, 256, 0, stream>>>(wx0, u0, bg0, bu0, zeta0, nu0, lambd0,
                                      gamma0, w1, u1, bg1, bu1, zeta1, nu1,
                                      lambd1, gamma1, out, hn);
}